// Round 5
// baseline (307.074 us; speedup 1.0000x reference)
//
#include <hip/hip_runtime.h>
#include <cmath>

// GPTNeoXRoutedMLP: N=2048 tokens, H=1024, F=4096, E=8, topk=2.
// R5: no weight pre-pass. GEMMs read f32 weights directly; B staged via
// VGPR (f32x4 loads) -> v_cvt_pk_bf16_f32 -> swizzled ds_write_b128.
// A staged via global_load_lds(16B) (pre-swizzled source). Counted-vmcnt
// raw barriers keep next-next B-tile loads in flight across the barrier.

#define H_DIM 1024
#define F_DIM 4096
#define E_NUM 8
#define N_TOK 2048
#define BK 64
#define MAX_SLOTS 5120
#define MAX_MT (MAX_SLOTS / 128)   // 40 row tiles
#define G1_GRID (MAX_MT * 32)      // 1280
#define G2_GRID (MAX_MT * 16)      // 640

typedef short s16x8 __attribute__((ext_vector_type(8)));
typedef float f32x4 __attribute__((ext_vector_type(4)));

__device__ __forceinline__ unsigned short f2bf(float f) {
  unsigned int u = __float_as_uint(f);
  u += 0x7fffu + ((u >> 16) & 1u);   // RNE
  return (unsigned short)(u >> 16);
}

__device__ __forceinline__ void gload_lds16(const void* g, void* l) {
  __builtin_amdgcn_global_load_lds(
      (const __attribute__((address_space(1))) unsigned int*)g,
      (__attribute__((address_space(3))) unsigned int*)l, 16, 0, 0);
}

__device__ __forceinline__ int xcd_swz(int orig, int nwg) {
  const int cpx = nwg >> 3;   // nwg multiple of 8 (1280 / 640)
  return (orig & 7) * cpx + (orig >> 3);
}

__device__ __forceinline__ float fast_gelu(float v) {
  const float w = v * (1.0f + 0.044715f * v * v);
  const float t = __expf(-1.5957691216f * w);
  return v / (1.0f + t);
}

__device__ __forceinline__ unsigned int pk_bf16(float lo, float hi) {
  unsigned int r;
  asm("v_cvt_pk_bf16_f32 %0, %1, %2" : "=v"(r) : "v"(lo), "v"(hi));
  return r;
}

// ---------------- prep: x f32->bf16 (1024 blk) | router (512 blk) ----------------
__global__ __launch_bounds__(256) void prep_k(
    const float* __restrict__ x, unsigned short* __restrict__ xb,
    const float* __restrict__ rw, int* __restrict__ meta,
    int* __restrict__ topk_e, float* __restrict__ topk_s) {
  const int b = blockIdx.x;
  const int t = threadIdx.x;
  if (b < 1024) {  // x f32 -> bf16
    const size_t i = (((size_t)b) * 256 + t) * 8;
    f32x4 a = *(const f32x4*)(x + i);
    f32x4 c = *(const f32x4*)(x + i + 4);
    s16x8 u;
#pragma unroll
    for (int j = 0; j < 4; ++j) { u[j] = (short)f2bf(a[j]); u[4 + j] = (short)f2bf(c[j]); }
    *(s16x8*)&xb[i] = u;
    return;
  }
  // router: one token per wave
  const int n = (b - 1024) * 4 + (t >> 6);
  const int l = t & 63;
  float part[E_NUM];
#pragma unroll
  for (int e = 0; e < E_NUM; ++e) part[e] = 0.f;
  const float* xr = x + (size_t)n * H_DIM;
  for (int h = l; h < H_DIM; h += 64) {
    const float xv = xr[h];
    const float* rwr = rw + h * E_NUM;
#pragma unroll
    for (int e = 0; e < E_NUM; ++e) part[e] += xv * rwr[e];
  }
#pragma unroll
  for (int e = 0; e < E_NUM; ++e) {
#pragma unroll
    for (int off = 32; off > 0; off >>= 1) part[e] += __shfl_down(part[e], off);
  }
  if (l == 0) {
    float v0 = -3.4e38f, v1 = -3.4e38f;
    int i0 = 0, i1 = 0;
#pragma unroll
    for (int e = 0; e < E_NUM; ++e) {
      float v = part[e];
      if (v > v0) { v1 = v0; i1 = i0; v0 = v; i0 = e; }   // strict >: lowest index wins ties
      else if (v > v1) { v1 = v; i1 = e; }
    }
    const float e1 = expf(v1 - v0);
    const float inv = 1.f / (1.f + e1);
    topk_e[2 * n] = i0; topk_e[2 * n + 1] = i1;
    topk_s[2 * n] = inv; topk_s[2 * n + 1] = e1 * inv;
    atomicAdd(&meta[i0], 1);
    atomicAdd(&meta[i1], 1);
  }
}

// ---------------- Scatter (slot_token pre-init to -1 via memset 0xFF) ----------------
__global__ __launch_bounds__(256) void scatter_k(
    int* __restrict__ meta, const int* __restrict__ topk_e,
    const float* __restrict__ topk_s, int* __restrict__ slot_token,
    float* __restrict__ slot_score) {
  __shared__ int soff[9];
  __shared__ int scur[8];
  const int t = threadIdx.x;
  if (t == 0) {
    int acc = 0;
    for (int e = 0; e < E_NUM; ++e) {
      soff[e] = acc;
      meta[8 + e] = acc;
      acc += ((meta[e] + 127) / 128) * 128;
    }
    soff[8] = acc;
    meta[16] = acc;
  }
  if (t < 8) scur[t] = 0;
  __syncthreads();
  for (int a = t; a < N_TOK * 2; a += 256) {
    const int e = topk_e[a];
    const int pos = atomicAdd(&scur[e], 1);
    const int slot = soff[e] + pos;
    slot_token[slot] = a >> 1;
    slot_score[slot] = topk_s[a];
  }
}

// ============ GEMM1: h = gelu(xb[gather] @ w1[e] + b1), w1 f32 consumed direct ============
__global__ __launch_bounds__(256, 2) void gemm1_f(
    const unsigned short* __restrict__ xb, const float* __restrict__ w1,
    const float* __restrict__ b1, const int* __restrict__ meta,
    const int* __restrict__ slot_token, unsigned short* __restrict__ hbuf) {
  __shared__ __align__(16) unsigned short Al[2 * 8192];  // [2][128][64]
  __shared__ __align__(16) unsigned short Bl[2 * 8192];  // [2][128cols][64k]
  const int total = meta[16];
  const int wgid = xcd_swz(blockIdx.x, G1_GRID);
  const int mt = wgid >> 5, nt = wgid & 31;
  const int m0 = mt * 128;
  if (m0 >= total) return;
  int exp = 0;
#pragma unroll
  for (int e = 1; e < E_NUM; ++e) if (m0 >= meta[8 + e]) exp = e;
  const int n0 = nt * 128;
  const int t = threadIdx.x, w = t >> 6, l = t & 63;
  const int wm = w >> 1, wn = w & 1, lr = l & 15, lg = l >> 4;
  const int sr = l >> 3, sc = l & 7;

  // A gather sources (pre-swizzled chunk so linear LDS dest + swizzled read match)
  const unsigned short* srcA[4];
#pragma unroll
  for (int i = 0; i < 4; ++i) {
    const int r = (w * 4 + i) * 8 + sr;
    int tk = slot_token[m0 + r]; if (tk < 0) tk = 0;
    srcA[i] = xb + (size_t)tk * H_DIM + (sc ^ sr) * 8;
  }
  // B staging geometry: thread owns k-chunk kg (8 rows) x 4 cols c4..c4+3
  const int kg = (t >> 3) & 7;
  const int cg = (t & 7) | ((t >> 6) << 3);
  const int c4 = cg * 4;
  const float* pB = w1 + (size_t)exp * H_DIM * F_DIM + (size_t)(kg * 8) * F_DIM + n0 + c4;

  const f32x4 fzero = {0.f, 0.f, 0.f, 0.f};
  f32x4 acc[4][4];
#pragma unroll
  for (int a = 0; a < 4; ++a)
#pragma unroll
    for (int b = 0; b < 4; ++b) acc[a][b] = fzero;

#define LOADB1(kt, v)                                                      \
  _Pragma("unroll") for (int r = 0; r < 8; ++r)                            \
      v[r] = *(const f32x4*)(pB + (size_t)((kt) * BK + r) * F_DIM);
#define CVTW1(v, Bd)                                                       \
  _Pragma("unroll") for (int j = 0; j < 4; ++j) {                          \
    int4 pk;                                                               \
    pk.x = (int)pk_bf16(v[0][j], v[1][j]);                                 \
    pk.y = (int)pk_bf16(v[2][j], v[3][j]);                                 \
    pk.z = (int)pk_bf16(v[4][j], v[5][j]);                                 \
    pk.w = (int)pk_bf16(v[6][j], v[7][j]);                                 \
    const int col = c4 + j;                                                \
    *(int4*)&(Bd)[col * 64 + ((kg ^ (col & 7)) << 3)] = pk;                \
  }
#define GLA1(kt, Ad)                                                       \
  _Pragma("unroll") for (int i = 0; i < 4; ++i)                            \
      gload_lds16(srcA[i] + (kt) * BK, (Ad) + (w * 4 + i) * 512);
#define MFMA1(Ac, Bc)                                                      \
  _Pragma("unroll") for (int kk = 0; kk < 2; ++kk) {                       \
    s16x8 af[4], bb[4];                                                    \
    _Pragma("unroll") for (int fm = 0; fm < 4; ++fm) {                     \
      const int row = wm * 64 + fm * 16 + lr;                              \
      af[fm] = *(const s16x8*)&(Ac)[row * 64 + (((kk * 4 + lg) ^ (lr & 7)) * 8)]; \
    }                                                                      \
    _Pragma("unroll") for (int fn = 0; fn < 4; ++fn) {                     \
      const int row = wn * 64 + fn * 16 + lr;                              \
      bb[fn] = *(const s16x8*)&(Bc)[row * 64 + (((kk * 4 + lg) ^ (lr & 7)) * 8)]; \
    }                                                                      \
    _Pragma("unroll") for (int fm = 0; fm < 4; ++fm)                       \
      _Pragma("unroll") for (int fn = 0; fn < 4; ++fn)                     \
        acc[fm][fn] = __builtin_amdgcn_mfma_f32_16x16x32_bf16(af[fm], bb[fn], acc[fm][fn], 0, 0, 0); \
  }

  const int NT = H_DIM / BK;  // 16
  f32x4 vP[8], vQ[8];
  LOADB1(0, vP)
  LOADB1(1, vQ)
  GLA1(0, Al)
  CVTW1(vP, Bl)
  __syncthreads();

  for (int kt = 0; kt < NT; kt += 2) {
    // even step: compute buf0, prefetch kt+1 into buf1
    GLA1(kt + 1, Al + 8192)
    if (kt + 2 < NT) { LOADB1(kt + 2, vP) }
    CVTW1(vQ, Bl + 8192)
    MFMA1(Al, Bl)
    if (kt + 2 < NT) asm volatile("s_waitcnt vmcnt(8)" ::: "memory");
    else             asm volatile("s_waitcnt vmcnt(0)" ::: "memory");
    asm volatile("s_waitcnt lgkmcnt(0)" ::: "memory");
    __builtin_amdgcn_s_barrier();
    // odd step: compute buf1, prefetch kt+2 into buf0
    if (kt + 2 < NT) {
      GLA1(kt + 2, Al)
      if (kt + 3 < NT) { LOADB1(kt + 3, vQ) }
      CVTW1(vP, Bl)
    }
    MFMA1(Al + 8192, Bl + 8192)
    if (kt + 2 < NT) {
      asm volatile("s_waitcnt vmcnt(8)" ::: "memory");
      asm volatile("s_waitcnt lgkmcnt(0)" ::: "memory");
      __builtin_amdgcn_s_barrier();
    }
  }
  asm volatile("s_waitcnt vmcnt(0) lgkmcnt(0)" ::: "memory");

#pragma unroll
  for (int fn = 0; fn < 4; ++fn) {
    const int col = n0 + wn * 64 + fn * 16 + lr;
    const float bias = b1[exp * F_DIM + col];
#pragma unroll
    for (int fm = 0; fm < 4; ++fm) {
      const int rbase = m0 + wm * 64 + fm * 16 + lg * 4;
#pragma unroll
      for (int i = 0; i < 4; ++i) {
        hbuf[(size_t)(rbase + i) * F_DIM + col] = f2bf(fast_gelu(acc[fm][fn][i] + bias));
      }
    }
  }
}

// ============ GEMM2: out[token] += s*(hbuf @ w2[e] + b2), w2 f32 direct, BN=64 ============
__global__ __launch_bounds__(256, 3) void gemm2_f(
    const unsigned short* __restrict__ hbuf, const float* __restrict__ w2,
    const float* __restrict__ b2, const int* __restrict__ meta,
    const int* __restrict__ slot_token, const float* __restrict__ slot_score,
    float* __restrict__ out) {
  __shared__ __align__(16) unsigned short Al[2 * 8192];  // [2][128][64]
  __shared__ __align__(16) unsigned short Bl[2 * 4096];  // [2][64cols][64k]
  const int total = meta[16];
  const int wgid = xcd_swz(blockIdx.x, G2_GRID);
  const int mt = wgid >> 4, nt = wgid & 15;
  const int m0 = mt * 128;
  if (m0 >= total) return;
  int exp = 0;
#pragma unroll
  for (int e = 1; e < E_NUM; ++e) if (m0 >= meta[8 + e]) exp = e;
  const int n0 = nt * 64;
  const int t = threadIdx.x, w = t >> 6, l = t & 63;
  const int wm = w >> 1, wn = w & 1, lr = l & 15, lg = l >> 4;
  const int sr = l >> 3, sc = l & 7;

  const unsigned short* srcA[4];
#pragma unroll
  for (int i = 0; i < 4; ++i) {
    const int r = (w * 4 + i) * 8 + sr;
    srcA[i] = hbuf + (size_t)(m0 + r) * F_DIM + (sc ^ sr) * 8;
  }
  // B staging: thread owns half-chunk (kg, kh: 4 k-rows) x 4 cols
  const int c4 = (t & 15) * 4;
  const int kgh = t >> 4;            // 0..15
  const int kg = kgh & 7, kh = kgh >> 3;
  const float* pB = w2 + (size_t)exp * F_DIM * H_DIM + (size_t)(kg * 8 + kh * 4) * H_DIM + n0 + c4;

  const f32x4 fzero = {0.f, 0.f, 0.f, 0.f};
  f32x4 acc[4][2];
#pragma unroll
  for (int a = 0; a < 4; ++a)
#pragma unroll
    for (int b = 0; b < 2; ++b) acc[a][b] = fzero;

#define LOADB2(kt, v)                                                      \
  _Pragma("unroll") for (int r = 0; r < 4; ++r)                            \
      v[r] = *(const f32x4*)(pB + (size_t)((kt) * BK + r) * H_DIM);
#define CVTW2(v, Bd)                                                       \
  _Pragma("unroll") for (int j = 0; j < 4; ++j) {                          \
    int2 pk;                                                               \
    pk.x = (int)pk_bf16(v[0][j], v[1][j]);                                 \
    pk.y = (int)pk_bf16(v[2][j], v[3][j]);                                 \
    const int col = c4 + j;                                                \
    *(int2*)&(Bd)[col * 64 + ((kg ^ (col & 7)) << 3) + kh * 4] = pk;       \
  }
#define GLA2(kt, Ad)                                                       \
  _Pragma("unroll") for (int i = 0; i < 4; ++i)                            \
      gload_lds16(srcA[i] + (kt) * BK, (Ad) + (w * 4 + i) * 512);
#define MFMA2(Ac, Bc)                                                      \
  _Pragma("unroll") for (int kk = 0; kk < 2; ++kk) {                       \
    s16x8 af[4], bb[2];                                                    \
    _Pragma("unroll") for (int fm = 0; fm < 4; ++fm) {                     \
      const int row = wm * 64 + fm * 16 + lr;                              \
      af[fm] = *(const s16x8*)&(Ac)[row * 64 + (((kk * 4 + lg) ^ (lr & 7)) * 8)]; \
    }                                                                      \
    _Pragma("unroll") for (int fn = 0; fn < 2; ++fn) {                     \
      const int row = wn * 32 + fn * 16 + lr;                              \
      bb[fn] = *(const s16x8*)&(Bc)[row * 64 + (((kk * 4 + lg) ^ (lr & 7)) * 8)]; \
    }                                                                      \
    _Pragma("unroll") for (int fm = 0; fm < 4; ++fm)                       \
      _Pragma("unroll") for (int fn = 0; fn < 2; ++fn)                     \
        acc[fm][fn] = __builtin_amdgcn_mfma_f32_16x16x32_bf16(af[fm], bb[fn], acc[fm][fn], 0, 0, 0); \
  }

  const int NT = F_DIM / BK;  // 64
  f32x4 vP[4], vQ[4];
  LOADB2(0, vP)
  LOADB2(1, vQ)
  GLA2(0, Al)
  CVTW2(vP, Bl)
  __syncthreads();

  for (int kt = 0; kt < NT; kt += 2) {
    GLA2(kt + 1, Al + 8192)
    if (kt + 2 < NT) { LOADB2(kt + 2, vP) }
    CVTW2(vQ, Bl + 4096)
    MFMA2(Al, Bl)
    if (kt + 2 < NT) asm volatile("s_waitcnt vmcnt(4)" ::: "memory");
    else             asm volatile("s_waitcnt vmcnt(0)" ::: "memory");
    asm volatile("s_waitcnt lgkmcnt(0)" ::: "memory");
    __builtin_amdgcn_s_barrier();
    if (kt + 2 < NT) {
      GLA2(kt + 2, Al)
      if (kt + 3 < NT) { LOADB2(kt + 3, vQ) }
      CVTW2(vP, Bl)
    }
    MFMA2(Al + 8192, Bl + 4096)
    if (kt + 2 < NT) {
      asm volatile("s_waitcnt vmcnt(4)" ::: "memory");
      asm volatile("s_waitcnt lgkmcnt(0)" ::: "memory");
      __builtin_amdgcn_s_barrier();
    }
  }
  asm volatile("s_waitcnt vmcnt(0) lgkmcnt(0)" ::: "memory");

#pragma unroll
  for (int fm = 0; fm < 4; ++fm) {
    const int rbase = m0 + wm * 64 + fm * 16 + lg * 4;
    int toks[4]; float ss[4];
#pragma unroll
    for (int i = 0; i < 4; ++i) {
      toks[i] = slot_token[rbase + i];
      ss[i] = slot_score[rbase + i];
    }
#pragma unroll
    for (int fn = 0; fn < 2; ++fn) {
      const int col = n0 + wn * 32 + fn * 16 + lr;
      const float b2v = b2[exp * H_DIM + col];
#pragma unroll
      for (int i = 0; i < 4; ++i) {
        if (toks[i] >= 0)
          atomicAdd(out + (size_t)toks[i] * H_DIM + col, ss[i] * (acc[fm][fn][i] + b2v));
      }
    }
  }
}

extern "C" void kernel_launch(void* const* d_in, const int* in_sizes, int n_in,
                              void* d_out, int out_size, void* d_ws, size_t ws_size,
                              hipStream_t stream) {
  const float* x  = (const float*)d_in[0];
  const float* rw = (const float*)d_in[1];
  const float* w1 = (const float*)d_in[2];
  const float* b1 = (const float*)d_in[3];
  const float* w2 = (const float*)d_in[4];
  const float* b2 = (const float*)d_in[5];
  float* out = (float*)d_out;
  char* ws = (char*)d_ws;

  int*   meta       = (int*)ws;
  int*   topk_e     = (int*)(ws + 4096);
  float* topk_s     = (float*)(ws + 20480);
  int*   slot_token = (int*)(ws + 36864);
  float* slot_score = (float*)(ws + 57344);
  unsigned short* xb   = (unsigned short*)(ws + (1ull << 20));
  unsigned short* hbuf = (unsigned short*)(ws + (8ull << 20));

  hipMemsetAsync(meta, 0, 256, stream);
  hipMemsetAsync(slot_token, 0xFF, MAX_SLOTS * sizeof(int), stream);
  hipMemsetAsync(out, 0, (size_t)N_TOK * H_DIM * sizeof(float), stream);

  prep_k<<<1024 + 512, 256, 0, stream>>>(x, xb, rw, meta, topk_e, topk_s);
  scatter_k<<<1, 256, 0, stream>>>(meta, topk_e, topk_s, slot_token, slot_score);
  gemm1_f<<<G1_GRID, 256, 0, stream>>>(xb, w1, b1, meta, slot_token, hbuf);
  gemm2_f<<<G2_GRID, 256, 0, stream>>>(hbuf, w2, b2, meta, slot_token, slot_score, out);
}